// Round 6
// baseline (1651.761 us; speedup 1.0000x reference)
//
#include <hip/hip_runtime.h>
#include <cstdint>

// r_full[401][128]: rows 0..199 = coeff@bases, 200..399 = -(coeff@bases), 400 = self_rel
__global__ void k_rfull(const float* __restrict__ coeff, const float* __restrict__ bases,
                        const float* __restrict__ selfr, float* __restrict__ rfull) {
  int row = blockIdx.x, c = threadIdx.x;
  float v;
  if (row == 400) {
    v = selfr[c];
  } else {
    int rr = row < 200 ? row : row - 200;
    float s = 0.f;
#pragma unroll 10
    for (int b = 0; b < 50; ++b) s += coeff[rr * 50 + b] * bases[b * 128 + c];
    v = (row < 200) ? s : -s;
  }
  rfull[row * 128 + c] = v;
}

// out[r][c] = sum_k A[r][k]*B[k][c], K=128, N=128 (relation chain)
__global__ void k_rmm(const float* __restrict__ A, const float* __restrict__ B,
                      float* __restrict__ out) {
  int r = blockIdx.x, c = threadIdx.x;
  float s = 0.f;
#pragma unroll 8
  for (int k = 0; k < 128; ++k) s += A[r * 128 + k] * B[k * 128 + c];
  out[r * 128 + c] = s;
}

// ---- CSR build over (dst, class) keys ----
__global__ void k_hist(const int* __restrict__ ei, const int* __restrict__ y,
                       int* __restrict__ counts, int nE) {
  int e = blockIdx.x * blockDim.x + threadIdx.x;
  if (e >= nE) return;
  int dst = ei[nE + e], k = y[e];
  atomicAdd(&counts[dst * 3 + k], 1);
}

// phase 1: per-block exclusive scan (block-local), block total out
__global__ void k_scan1(const int* __restrict__ counts, int* __restrict__ local,
                        int* __restrict__ blockSums, int n) {
  __shared__ int sdata[1024];
  int tid = threadIdx.x;
  int i = blockIdx.x * 1024 + tid;
  int v = (i < n) ? counts[i] : 0;
  sdata[tid] = v;
  __syncthreads();
  for (int off = 1; off < 1024; off <<= 1) {
    int t = (tid >= off) ? sdata[tid - off] : 0;
    __syncthreads();
    sdata[tid] += t;
    __syncthreads();
  }
  if (i < n) local[i] = sdata[tid] - v;   // block-local exclusive
  if (tid == 1023) blockSums[blockIdx.x] = sdata[1023];
}

// phase 2: single block scans block totals (nb <= 1024), writes carries + total
__global__ void k_scan2(const int* __restrict__ blockSums, int* __restrict__ carries,
                        int* __restrict__ offsets, int n, int nb) {
  __shared__ int sdata[1024];
  int tid = threadIdx.x;
  int v = (tid < nb) ? blockSums[tid] : 0;
  sdata[tid] = v;
  __syncthreads();
  for (int off = 1; off < 1024; off <<= 1) {
    int t = (tid >= off) ? sdata[tid - off] : 0;
    __syncthreads();
    sdata[tid] += t;
    __syncthreads();
  }
  if (tid < nb) carries[tid] = sdata[tid] - v;  // exclusive carry per block
  if (tid == 1023) offsets[n] = sdata[1023];    // grand total
}

// phase 3: add carry, write offsets + cursor copy
__global__ void k_scan3(const int* __restrict__ local, const int* __restrict__ carries,
                        int* __restrict__ offsets, int* __restrict__ cursor, int n) {
  int i = blockIdx.x * 1024 + threadIdx.x;
  if (i >= n) return;
  int v = local[i] + carries[blockIdx.x];
  offsets[i] = v;
  cursor[i] = v;
}

__global__ void k_fill(const int* __restrict__ ei, const int* __restrict__ y,
                       int* __restrict__ cursor, int* __restrict__ bucket, int nE) {
  int e = blockIdx.x * blockDim.x + threadIdx.x;
  if (e >= nE) return;
  int dst = ei[nE + e], k = y[e];
  int slot = atomicAdd(&cursor[dst * 3 + k], 1);
  bucket[slot] = e;
}

// Fused per-layer kernel: one workgroup owns 64 dst rows.
// For each class k: build As[64][128] = segment-sum of (x[src]-r[type]) over class-k
// in-edges (CSR walk, gathers L3-served), then As @ W[k] accumulated in registers.
// Single C store — T never touches HBM.
__global__ __launch_bounds__(256) void k_layer(const float* __restrict__ x, const int* __restrict__ ids,
                                               const float* __restrict__ r,
                                               const int* __restrict__ ei, const int* __restrict__ et,
                                               const int* __restrict__ offsets, const int* __restrict__ bucket,
                                               const float* __restrict__ W, float* __restrict__ C, int M) {
  __shared__ float As[64][128];
  __shared__ float Bs[32][128];
  const int tid = threadIdx.x;
  const int m0 = blockIdx.x * 64;
  const int wave = tid >> 6, lane = tid & 63;
  const int tx = tid & 31, ty = tid >> 5;
  const int c = lane * 2;
  float acc[8][4];
#pragma unroll
  for (int i = 0; i < 8; ++i)
#pragma unroll
    for (int j = 0; j < 4; ++j) acc[i][j] = 0.f;

  for (int k = 0; k < 3; ++k) {
    // ---- stage 1: aggregate class-k messages into As (each wave owns rows wave,wave+4,...) ----
    for (int row = wave; row < 64; row += 4) {
      int dst = m0 + row;
      float ax = 0.f, ay = 0.f;
      if (dst < M) {
        int s = offsets[dst * 3 + k];
        int e = offsets[dst * 3 + k + 1];
        int srcN = 0, tN = 0;
        int j = s;
        if (j < e) { int ed = bucket[j]; srcN = ei[ed]; tN = et[ed]; }
        while (j < e) {
          int src = srcN, t = tN;
          ++j;
          if (j < e) { int ed = bucket[j]; srcN = ei[ed]; tN = et[ed]; }  // prefetch next indices
          if (ids) src = ids[src];
          float2 hv = *(const float2*)&x[(size_t)src * 128 + c];
          float2 rv = *(const float2*)&r[(size_t)t * 128 + c];
          ax += hv.x - rv.x;
          ay += hv.y - rv.y;
        }
      }
      As[row][c] = ax;
      As[row][c + 1] = ay;
    }
    __syncthreads();
    // ---- stage 2: acc += As(64x128) @ W_k(128x128) ----
    const float* Wk = W + (size_t)k * 16384;
    for (int kb = 0; kb < 128; kb += 32) {
#pragma unroll
      for (int jj = 0; jj < 4; ++jj) {
        int idx = tid + 256 * jj;
        int kr = idx >> 5, c4 = (idx & 31) * 4;
        *(float4*)&Bs[kr][c4] = *(const float4*)&Wk[(size_t)(kb + kr) * 128 + c4];
      }
      __syncthreads();
#pragma unroll
      for (int kk = 0; kk < 32; ++kk) {
        float4 bv = *(const float4*)&Bs[kk][tx * 4];
#pragma unroll
        for (int i = 0; i < 8; ++i) {
          float a = As[ty + 8 * i][kb + kk];
          acc[i][0] += a * bv.x; acc[i][1] += a * bv.y;
          acc[i][2] += a * bv.z; acc[i][3] += a * bv.w;
        }
      }
      __syncthreads();   // protects Bs (next kb) and As (next class)
    }
  }
#pragma unroll
  for (int i = 0; i < 8; ++i) {
    int m = m0 + ty + 8 * i;
    if (m < M) {
      float4 v = make_float4(acc[i][0], acc[i][1], acc[i][2], acc[i][3]);
      *(float4*)&C[(size_t)m * 128 + tx * 4] = v;
    }
  }
}

// per-column sum & sumsq over rows; 256 thr = 2 rows x 128 cols per iter
__global__ void k_stats(const float* __restrict__ agg, float* __restrict__ sums,
                        float* __restrict__ sumsq, int M) {
  int c = threadIdx.x & 127;
  int g = threadIdx.x >> 7;
  int row0 = blockIdx.x * 256;
  int rend = min(row0 + 256, M);
  float s = 0.f, q = 0.f;
  for (int r = row0 + g; r < rend; r += 2) {
    float v = agg[(size_t)r * 128 + c];
    s += v; q += v * v;
  }
  atomicAdd(&sums[c], s);
  atomicAdd(&sumsq[c], q);
}

__global__ void k_finalize(const float* __restrict__ sums, const float* __restrict__ sumsq,
                           const float* __restrict__ gamma, const float* __restrict__ beta,
                           float* __restrict__ scale, float* __restrict__ bias, float invN) {
  int c = threadIdx.x;
  float mean = sums[c] * invN;
  float var = fmaxf(sumsq[c] * invN - mean * mean, 0.f);
  float sc = rsqrtf(var + 1e-5f) * gamma[c];
  scale[c] = sc;
  bias[c] = beta[c] - mean * sc;
}

__global__ void k_norm(const float* __restrict__ agg, const float* __restrict__ scale,
                       const float* __restrict__ bias, float* __restrict__ x, int total) {
  int idx = blockIdx.x * blockDim.x + threadIdx.x;
  if (idx >= total) return;
  int c = idx & 127;
  x[idx] = tanhf(fmaf(agg[idx], scale[c], bias[c]));
}

// one wave per triple: sum_d |x[h]+r[rel]-x[t]|
__global__ void k_score(const float* __restrict__ x, const float* __restrict__ r,
                        const int* __restrict__ triples, float* __restrict__ out, int nT) {
  int gid = blockIdx.x * blockDim.x + threadIdx.x;
  int t = gid >> 6;
  if (t >= nT) return;
  int lane = gid & 63;
  int h = triples[t * 3], rel = triples[t * 3 + 1], tl = triples[t * 3 + 2];
  int d = lane * 2;
  float2 a = *(const float2*)&x[(size_t)h * 128 + d];
  float2 b = *(const float2*)&r[(size_t)rel * 128 + d];
  float2 cc = *(const float2*)&x[(size_t)tl * 128 + d];
  float s = fabsf(a.x + b.x - cc.x) + fabsf(a.y + b.y - cc.y);
#pragma unroll
  for (int off = 32; off > 0; off >>= 1) s += __shfl_down(s, off);
  if (lane == 0) out[t] = s;
}

extern "C" void kernel_launch(void* const* d_in, const int* in_sizes, int n_in,
                              void* d_out, int out_size, void* d_ws, size_t ws_size,
                              hipStream_t stream) {
  const float* ent   = (const float*)d_in[0];
  const float* bases = (const float*)d_in[1];
  const float* coeff = (const float*)d_in[2];
  const float* selfr = (const float*)d_in[3];
  const float* W1    = (const float*)d_in[4];
  const float* relw1 = (const float*)d_in[5];
  const float* g1    = (const float*)d_in[6];
  const float* b1    = (const float*)d_in[7];
  const float* W2    = (const float*)d_in[8];
  const float* relw2 = (const float*)d_in[9];
  const float* g2    = (const float*)d_in[10];
  const float* b2    = (const float*)d_in[11];
  const int* ent_ids = (const int*)d_in[12];
  const int* ei      = (const int*)d_in[13];
  const int* et      = (const int*)d_in[14];
  const int* yk      = (const int*)d_in[15];
  const int* triples = (const int*)d_in[16];

  const int M  = in_sizes[0] / 128;   // 100000 entities
  const int nE = in_sizes[14];        // 800000 edges
  const int nT = in_sizes[16] / 3;    // 4096 triples
  const int nKeys = M * 3;
  const int nScanBlocks = (nKeys + 1023) / 1024;  // 293

  // workspace layout (~110 MB)
  float* p = (float*)d_ws;
  float* rfull = p; p += 401 * 128;
  float* r1    = p; p += 401 * 128;
  float* r2    = p; p += 401 * 128;
  float* agg1  = p; p += (size_t)M * 128;   // layer-1 agg -> x1 (in-place norm)
  float* agg2  = p; p += (size_t)M * 128;   // layer-2 agg -> x2 (in-place norm)
  float* sums  = p; p += 128;
  float* sumsq = p; p += 128;
  float* scale = p; p += 128;
  float* bias  = p; p += 128;
  int* counts  = (int*)p;              // nKeys
  int* offsets = counts + nKeys;       // nKeys + 1
  int* cursor  = offsets + nKeys + 1;  // nKeys
  int* bucket  = cursor + nKeys;       // nE
  int* slocal  = bucket + nE;          // nKeys (scan scratch)
  int* sblock  = slocal + nKeys;       // nScanBlocks (block totals)
  int* scarry  = sblock + nScanBlocks; // nScanBlocks (block carries)

  float* out = (float*)d_out;

  const int layerBlocks = (M + 63) / 64;
  const int statBlocks = (M + 255) / 256;
  const int total = M * 128;
  const int normBlocks = (total + 255) / 256;
  const int edgeBlocks = (nE + 255) / 256;

  // relation chain (shared by both layers + scoring)
  k_rfull<<<401, 128, 0, stream>>>(coeff, bases, selfr, rfull);
  k_rmm<<<401, 128, 0, stream>>>(rfull, relw1, r1);
  k_rmm<<<401, 128, 0, stream>>>(r1, relw2, r2);

  // CSR over (dst, class) — same graph both layers
  hipMemsetAsync(counts, 0, (size_t)nKeys * sizeof(int), stream);
  k_hist<<<edgeBlocks, 256, 0, stream>>>(ei, yk, counts, nE);
  k_scan1<<<nScanBlocks, 1024, 0, stream>>>(counts, slocal, sblock, nKeys);
  k_scan2<<<1, 1024, 0, stream>>>(sblock, scarry, offsets, nKeys, nScanBlocks);
  k_scan3<<<nScanBlocks, 1024, 0, stream>>>(slocal, scarry, offsets, cursor, nKeys);
  k_fill<<<edgeBlocks, 256, 0, stream>>>(ei, yk, cursor, bucket, nE);

  // ---- layer 1: x_in = ent (via ent_ids), r = rfull -> agg1 ----
  k_layer<<<layerBlocks, 256, 0, stream>>>(ent, ent_ids, rfull, ei, et, offsets, bucket, W1, agg1, M);
  hipMemsetAsync(sums, 0, 256 * sizeof(float), stream);
  k_stats<<<statBlocks, 256, 0, stream>>>(agg1, sums, sumsq, M);
  k_finalize<<<1, 128, 0, stream>>>(sums, sumsq, g1, b1, scale, bias, 1.0f / M);
  k_norm<<<normBlocks, 256, 0, stream>>>(agg1, scale, bias, agg1, total);   // agg1 -> x1

  // ---- layer 2: x_in = agg1 (=x1), r = r1 -> agg2 ----
  k_layer<<<layerBlocks, 256, 0, stream>>>(agg1, nullptr, r1, ei, et, offsets, bucket, W2, agg2, M);
  hipMemsetAsync(sums, 0, 256 * sizeof(float), stream);
  k_stats<<<statBlocks, 256, 0, stream>>>(agg2, sums, sumsq, M);
  k_finalize<<<1, 128, 0, stream>>>(sums, sumsq, g2, b2, scale, bias, 1.0f / M);
  k_norm<<<normBlocks, 256, 0, stream>>>(agg2, scale, bias, agg2, total);   // agg2 -> x2

  // ---- scoring ----
  k_score<<<(nT * 64 + 255) / 256, 256, 0, stream>>>(agg2, r2, triples, out, nT);
}

// Round 7
// 964.553 us; speedup vs baseline: 1.7125x; 1.7125x over previous
//
#include <hip/hip_runtime.h>
#include <cstdint>

// r_full[401][128]: rows 0..199 = coeff@bases, 200..399 = -(coeff@bases), 400 = self_rel
__global__ void k_rfull(const float* __restrict__ coeff, const float* __restrict__ bases,
                        const float* __restrict__ selfr, float* __restrict__ rfull) {
  int row = blockIdx.x, c = threadIdx.x;
  float v;
  if (row == 400) {
    v = selfr[c];
  } else {
    int rr = row < 200 ? row : row - 200;
    float s = 0.f;
#pragma unroll 10
    for (int b = 0; b < 50; ++b) s += coeff[rr * 50 + b] * bases[b * 128 + c];
    v = (row < 200) ? s : -s;
  }
  rfull[row * 128 + c] = v;
}

// out[r][c] = sum_k A[r][k]*B[k][c], K=128, N=128 (relation chain)
__global__ void k_rmm(const float* __restrict__ A, const float* __restrict__ B,
                      float* __restrict__ out) {
  int r = blockIdx.x, c = threadIdx.x;
  float s = 0.f;
#pragma unroll 8
  for (int k = 0; k < 128; ++k) s += A[r * 128 + k] * B[k * 128 + c];
  out[r * 128 + c] = s;
}

// ---- CSR build over (dst, class) keys ----
__global__ void k_hist(const int* __restrict__ ei, const int* __restrict__ y,
                       int* __restrict__ counts, int nE) {
  int e = blockIdx.x * blockDim.x + threadIdx.x;
  if (e >= nE) return;
  int dst = ei[nE + e], k = y[e];
  atomicAdd(&counts[dst * 3 + k], 1);
}

__global__ void k_scan1(const int* __restrict__ counts, int* __restrict__ local,
                        int* __restrict__ blockSums, int n) {
  __shared__ int sdata[1024];
  int tid = threadIdx.x;
  int i = blockIdx.x * 1024 + tid;
  int v = (i < n) ? counts[i] : 0;
  sdata[tid] = v;
  __syncthreads();
  for (int off = 1; off < 1024; off <<= 1) {
    int t = (tid >= off) ? sdata[tid - off] : 0;
    __syncthreads();
    sdata[tid] += t;
    __syncthreads();
  }
  if (i < n) local[i] = sdata[tid] - v;
  if (tid == 1023) blockSums[blockIdx.x] = sdata[1023];
}

__global__ void k_scan2(const int* __restrict__ blockSums, int* __restrict__ carries,
                        int* __restrict__ offsets, int n, int nb) {
  __shared__ int sdata[1024];
  int tid = threadIdx.x;
  int v = (tid < nb) ? blockSums[tid] : 0;
  sdata[tid] = v;
  __syncthreads();
  for (int off = 1; off < 1024; off <<= 1) {
    int t = (tid >= off) ? sdata[tid - off] : 0;
    __syncthreads();
    sdata[tid] += t;
    __syncthreads();
  }
  if (tid < nb) carries[tid] = sdata[tid] - v;
  if (tid == 1023) offsets[n] = sdata[1023];
}

__global__ void k_scan3(const int* __restrict__ local, const int* __restrict__ carries,
                        int* __restrict__ offsets, int* __restrict__ cursor, int n) {
  int i = blockIdx.x * 1024 + threadIdx.x;
  if (i >= n) return;
  int v = local[i] + carries[blockIdx.x];
  offsets[i] = v;
  cursor[i] = v;
}

// fill: packed[slot] = src | (type<<20)  (src<2^20, type<=400<2^12)
__global__ void k_fill(const int* __restrict__ ei, const int* __restrict__ et,
                       const int* __restrict__ y, int* __restrict__ cursor,
                       unsigned int* __restrict__ packed, int nE) {
  int e = blockIdx.x * blockDim.x + threadIdx.x;
  if (e >= nE) return;
  int dst = ei[nE + e], k = y[e];
  int slot = atomicAdd(&cursor[dst * 3 + k], 1);
  packed[slot] = (unsigned int)ei[e] | ((unsigned int)et[e] << 20);
}

// ---- gather-aggregate, wave per (dst,class) key, 4 waves/block ----
// dual-chain 2-edge unroll; single packed index load per edge.
// BIG path: writes T[dst*384 + k*128 + c]
__global__ __launch_bounds__(256) void k_aggBig(const float* __restrict__ x, const int* __restrict__ ids,
                                                const float* __restrict__ r,
                                                const int* __restrict__ offsets,
                                                const unsigned int* __restrict__ packed,
                                                float* __restrict__ T, int nKeys) {
  int key = blockIdx.x * 4 + (threadIdx.x >> 6);
  if (key >= nKeys) return;
  int lane = threadIdx.x & 63;
  int c = lane * 2;
  int dst = key / 3, k = key - dst * 3;
  int s = offsets[key], e = offsets[key + 1];
  float ax0 = 0.f, ay0 = 0.f, ax1 = 0.f, ay1 = 0.f;
  int j = s;
  for (; j + 1 < e; j += 2) {
    unsigned int p0 = packed[j], p1 = packed[j + 1];
    int s0 = p0 & 0xFFFFF, t0 = p0 >> 20;
    int s1 = p1 & 0xFFFFF, t1 = p1 >> 20;
    if (ids) { s0 = ids[s0]; s1 = ids[s1]; }
    float2 h0 = *(const float2*)&x[(size_t)s0 * 128 + c];
    float2 r0 = *(const float2*)&r[(size_t)t0 * 128 + c];
    float2 h1 = *(const float2*)&x[(size_t)s1 * 128 + c];
    float2 r1 = *(const float2*)&r[(size_t)t1 * 128 + c];
    ax0 += h0.x - r0.x; ay0 += h0.y - r0.y;
    ax1 += h1.x - r1.x; ay1 += h1.y - r1.y;
  }
  if (j < e) {
    unsigned int p0 = packed[j];
    int s0 = p0 & 0xFFFFF, t0 = p0 >> 20;
    if (ids) s0 = ids[s0];
    float2 h0 = *(const float2*)&x[(size_t)s0 * 128 + c];
    float2 r0 = *(const float2*)&r[(size_t)t0 * 128 + c];
    ax0 += h0.x - r0.x; ay0 += h0.y - r0.y;
  }
  float* tp = &T[(size_t)dst * 384 + k * 128 + c];
  tp[0] = ax0 + ax1;
  tp[1] = ay0 + ay1;
}

// SMALL path: one class per dispatch, writes T[dst*128 + c]
__global__ __launch_bounds__(256) void k_aggSmall(const float* __restrict__ x, const int* __restrict__ ids,
                                                  const float* __restrict__ r,
                                                  const int* __restrict__ offsets,
                                                  const unsigned int* __restrict__ packed,
                                                  float* __restrict__ T, int M, int kcls) {
  int dst = blockIdx.x * 4 + (threadIdx.x >> 6);
  if (dst >= M) return;
  int lane = threadIdx.x & 63;
  int c = lane * 2;
  int key = dst * 3 + kcls;
  int s = offsets[key], e = offsets[key + 1];
  float ax0 = 0.f, ay0 = 0.f, ax1 = 0.f, ay1 = 0.f;
  int j = s;
  for (; j + 1 < e; j += 2) {
    unsigned int p0 = packed[j], p1 = packed[j + 1];
    int s0 = p0 & 0xFFFFF, t0 = p0 >> 20;
    int s1 = p1 & 0xFFFFF, t1 = p1 >> 20;
    if (ids) { s0 = ids[s0]; s1 = ids[s1]; }
    float2 h0 = *(const float2*)&x[(size_t)s0 * 128 + c];
    float2 r0 = *(const float2*)&r[(size_t)t0 * 128 + c];
    float2 h1 = *(const float2*)&x[(size_t)s1 * 128 + c];
    float2 r1 = *(const float2*)&r[(size_t)t1 * 128 + c];
    ax0 += h0.x - r0.x; ay0 += h0.y - r0.y;
    ax1 += h1.x - r1.x; ay1 += h1.y - r1.y;
  }
  if (j < e) {
    unsigned int p0 = packed[j];
    int s0 = p0 & 0xFFFFF, t0 = p0 >> 20;
    if (ids) s0 = ids[s0];
    float2 h0 = *(const float2*)&x[(size_t)s0 * 128 + c];
    float2 r0 = *(const float2*)&r[(size_t)t0 * 128 + c];
    ax0 += h0.x - r0.x; ay0 += h0.y - r0.y;
  }
  float* tp = &T[(size_t)dst * 128 + c];
  tp[0] = ax0 + ax1;
  tp[1] = ay0 + ay1;
}

// C[M x 128] = A[M x 384] @ W(384x128, row-major = [W0;W1;W2]). No C readback.
__global__ __launch_bounds__(256) void k_gemm384(const float* __restrict__ A,
                                                 const float* __restrict__ B,
                                                 float* __restrict__ C, int M) {
  __shared__ float As[64][33];
  __shared__ float Bs[32][128];
  const int tid = threadIdx.x;
  const int m0 = blockIdx.x * 64;
  const int tx = tid & 31, ty = tid >> 5;
  float acc[8][4];
#pragma unroll
  for (int i = 0; i < 8; ++i)
#pragma unroll
    for (int j = 0; j < 4; ++j) acc[i][j] = 0.f;

  for (int kb = 0; kb < 384; kb += 32) {
#pragma unroll
    for (int j = 0; j < 2; ++j) {
      int idx = tid + 256 * j;
      int rr = idx >> 3, c4 = (idx & 7) * 4;
      int m = m0 + rr;
      float4 v = make_float4(0.f, 0.f, 0.f, 0.f);
      if (m < M) v = *(const float4*)&A[(size_t)m * 384 + kb + c4];
      As[rr][c4] = v.x; As[rr][c4 + 1] = v.y; As[rr][c4 + 2] = v.z; As[rr][c4 + 3] = v.w;
    }
#pragma unroll
    for (int j = 0; j < 4; ++j) {
      int idx = tid + 256 * j;
      int kr = idx >> 5, c4 = (idx & 31) * 4;
      *(float4*)&Bs[kr][c4] = *(const float4*)&B[(size_t)(kb + kr) * 128 + c4];
    }
    __syncthreads();
#pragma unroll
    for (int kk = 0; kk < 32; ++kk) {
      float4 bv = *(const float4*)&Bs[kk][tx * 4];
#pragma unroll
      for (int i = 0; i < 8; ++i) {
        float a = As[ty + 8 * i][kk];
        acc[i][0] += a * bv.x; acc[i][1] += a * bv.y;
        acc[i][2] += a * bv.z; acc[i][3] += a * bv.w;
      }
    }
    __syncthreads();
  }
#pragma unroll
  for (int i = 0; i < 8; ++i) {
    int m = m0 + ty + 8 * i;
    if (m < M) {
      float4 v = make_float4(acc[i][0], acc[i][1], acc[i][2], acc[i][3]);
      *(float4*)&C[(size_t)m * 128 + tx * 4] = v;
    }
  }
}

// C[M x 128] (+)= A[M x 128] @ B[128 x 128] (small path, accumulate)
__global__ __launch_bounds__(256) void k_gemm128(const float* __restrict__ A,
                                                 const float* __restrict__ B,
                                                 float* __restrict__ C, int M, int init) {
  __shared__ float As[64][33];
  __shared__ float Bs[32][128];
  const int tid = threadIdx.x;
  const int m0 = blockIdx.x * 64;
  const int tx = tid & 31, ty = tid >> 5;
  float acc[8][4];
#pragma unroll
  for (int i = 0; i < 8; ++i)
#pragma unroll
    for (int j = 0; j < 4; ++j) acc[i][j] = 0.f;

  for (int kb = 0; kb < 128; kb += 32) {
#pragma unroll
    for (int j = 0; j < 2; ++j) {
      int idx = tid + 256 * j;
      int rr = idx >> 3, c4 = (idx & 7) * 4;
      int m = m0 + rr;
      float4 v = make_float4(0.f, 0.f, 0.f, 0.f);
      if (m < M) v = *(const float4*)&A[(size_t)m * 128 + kb + c4];
      As[rr][c4] = v.x; As[rr][c4 + 1] = v.y; As[rr][c4 + 2] = v.z; As[rr][c4 + 3] = v.w;
    }
#pragma unroll
    for (int j = 0; j < 4; ++j) {
      int idx = tid + 256 * j;
      int kr = idx >> 5, c4 = (idx & 31) * 4;
      *(float4*)&Bs[kr][c4] = *(const float4*)&B[(size_t)(kb + kr) * 128 + c4];
    }
    __syncthreads();
#pragma unroll
    for (int kk = 0; kk < 32; ++kk) {
      float4 bv = *(const float4*)&Bs[kk][tx * 4];
#pragma unroll
      for (int i = 0; i < 8; ++i) {
        float a = As[ty + 8 * i][kk];
        acc[i][0] += a * bv.x; acc[i][1] += a * bv.y;
        acc[i][2] += a * bv.z; acc[i][3] += a * bv.w;
      }
    }
    __syncthreads();
  }
#pragma unroll
  for (int i = 0; i < 8; ++i) {
    int m = m0 + ty + 8 * i;
    if (m < M) {
      float4 v = make_float4(acc[i][0], acc[i][1], acc[i][2], acc[i][3]);
      if (!init) {
        float4 o = *(const float4*)&C[(size_t)m * 128 + tx * 4];
        v.x += o.x; v.y += o.y; v.z += o.z; v.w += o.w;
      }
      *(float4*)&C[(size_t)m * 128 + tx * 4] = v;
    }
  }
}

// per-column sum & sumsq over rows
__global__ void k_stats(const float* __restrict__ agg, float* __restrict__ sums,
                        float* __restrict__ sumsq, int M) {
  int c = threadIdx.x & 127;
  int g = threadIdx.x >> 7;
  int row0 = blockIdx.x * 256;
  int rend = min(row0 + 256, M);
  float s = 0.f, q = 0.f;
  for (int r = row0 + g; r < rend; r += 2) {
    float v = agg[(size_t)r * 128 + c];
    s += v; q += v * v;
  }
  atomicAdd(&sums[c], s);
  atomicAdd(&sumsq[c], q);
}

__global__ void k_finalize(const float* __restrict__ sums, const float* __restrict__ sumsq,
                           const float* __restrict__ gamma, const float* __restrict__ beta,
                           float* __restrict__ scale, float* __restrict__ bias, float invN) {
  int c = threadIdx.x;
  float mean = sums[c] * invN;
  float var = fmaxf(sumsq[c] * invN - mean * mean, 0.f);
  float sc = rsqrtf(var + 1e-5f) * gamma[c];
  scale[c] = sc;
  bias[c] = beta[c] - mean * sc;
}

__global__ void k_norm(const float* __restrict__ agg, const float* __restrict__ scale,
                       const float* __restrict__ bias, float* __restrict__ x, int total) {
  int idx = blockIdx.x * blockDim.x + threadIdx.x;
  if (idx >= total) return;
  int c = idx & 127;
  x[idx] = tanhf(fmaf(agg[idx], scale[c], bias[c]));
}

// one wave per triple: sum_d |x[h]+r[rel]-x[t]|
__global__ void k_score(const float* __restrict__ x, const float* __restrict__ r,
                        const int* __restrict__ triples, float* __restrict__ out, int nT) {
  int gid = blockIdx.x * blockDim.x + threadIdx.x;
  int t = gid >> 6;
  if (t >= nT) return;
  int lane = gid & 63;
  int h = triples[t * 3], rel = triples[t * 3 + 1], tl = triples[t * 3 + 2];
  int d = lane * 2;
  float2 a = *(const float2*)&x[(size_t)h * 128 + d];
  float2 b = *(const float2*)&r[(size_t)rel * 128 + d];
  float2 cc = *(const float2*)&x[(size_t)tl * 128 + d];
  float s = fabsf(a.x + b.x - cc.x) + fabsf(a.y + b.y - cc.y);
#pragma unroll
  for (int off = 32; off > 0; off >>= 1) s += __shfl_down(s, off);
  if (lane == 0) out[t] = s;
}

extern "C" void kernel_launch(void* const* d_in, const int* in_sizes, int n_in,
                              void* d_out, int out_size, void* d_ws, size_t ws_size,
                              hipStream_t stream) {
  const float* ent   = (const float*)d_in[0];
  const float* bases = (const float*)d_in[1];
  const float* coeff = (const float*)d_in[2];
  const float* selfr = (const float*)d_in[3];
  const float* W1    = (const float*)d_in[4];
  const float* relw1 = (const float*)d_in[5];
  const float* g1    = (const float*)d_in[6];
  const float* b1    = (const float*)d_in[7];
  const float* W2    = (const float*)d_in[8];
  const float* relw2 = (const float*)d_in[9];
  const float* g2    = (const float*)d_in[10];
  const float* b2    = (const float*)d_in[11];
  const int* ent_ids = (const int*)d_in[12];
  const int* ei      = (const int*)d_in[13];
  const int* et      = (const int*)d_in[14];
  const int* yk      = (const int*)d_in[15];
  const int* triples = (const int*)d_in[16];

  const int M  = in_sizes[0] / 128;   // 100000
  const int nE = in_sizes[14];        // 800000
  const int nT = in_sizes[16] / 3;    // 4096
  const int nKeys = M * 3;
  const int nScanBlocks = (nKeys + 1023) / 1024;

  // int scratch size (elements): counts, offsets(+1), cursor, slocal, sblock, scarry, packed
  const size_t intElems = (size_t)nKeys * 4 + 1 + 2 * nScanBlocks + nE;
  const size_t baseFloats = (size_t)401 * 128 * 3 + 512;
  const size_t bigBytes   = (baseFloats + (size_t)M * 128 + (size_t)M * 384) * 4 + intElems * 4;
  const bool   useBig     = ws_size >= bigBytes;

  float* p = (float*)d_ws;
  float* rfull = p; p += 401 * 128;
  float* r1    = p; p += 401 * 128;
  float* r2    = p; p += 401 * 128;
  float* sums  = p; p += 128;
  float* sumsq = p; p += 128;
  float* scale = p; p += 128;
  float* bias  = p; p += 128;
  float* agg1  = p; p += (size_t)M * 128;
  float* agg2; float* T;
  if (useBig) {
    T = p; p += (size_t)M * 384;
    agg2 = agg1;                       // layer-2 output overwrites x1 (dead by then)
  } else {
    agg2 = p; p += (size_t)M * 128;
    T    = p; p += (size_t)M * 128;
  }
  int* counts  = (int*)p;
  int* offsets = counts + nKeys;
  int* cursor  = offsets + nKeys + 1;
  int* slocal  = cursor + nKeys;
  int* sblock  = slocal + nKeys;
  int* scarry  = sblock + nScanBlocks;
  unsigned int* packed = (unsigned int*)(scarry + nScanBlocks);

  float* out = (float*)d_out;

  const int gemmBlocks = (M + 63) / 64;
  const int statBlocks = (M + 255) / 256;
  const int total = M * 128;
  const int normBlocks = (total + 255) / 256;
  const int edgeBlocks = (nE + 255) / 256;
  const int keyBlocks  = (nKeys + 3) / 4;
  const int dstBlocks  = (M + 3) / 4;

  // relation chain
  k_rfull<<<401, 128, 0, stream>>>(coeff, bases, selfr, rfull);
  k_rmm<<<401, 128, 0, stream>>>(rfull, relw1, r1);
  k_rmm<<<401, 128, 0, stream>>>(r1, relw2, r2);

  // CSR over (dst, class) with packed (src|type<<20) payload
  hipMemsetAsync(counts, 0, (size_t)nKeys * sizeof(int), stream);
  k_hist<<<edgeBlocks, 256, 0, stream>>>(ei, yk, counts, nE);
  k_scan1<<<nScanBlocks, 1024, 0, stream>>>(counts, slocal, sblock, nKeys);
  k_scan2<<<1, 1024, 0, stream>>>(sblock, scarry, offsets, nKeys, nScanBlocks);
  k_scan3<<<nScanBlocks, 1024, 0, stream>>>(slocal, scarry, offsets, cursor, nKeys);
  k_fill<<<edgeBlocks, 256, 0, stream>>>(ei, et, yk, cursor, packed, nE);

  if (useBig) {
    // ---- layer 1 ----
    k_aggBig<<<keyBlocks, 256, 0, stream>>>(ent, ent_ids, rfull, offsets, packed, T, nKeys);
    k_gemm384<<<gemmBlocks, 256, 0, stream>>>(T, W1, agg1, M);
    hipMemsetAsync(sums, 0, 256 * sizeof(float), stream);
    k_stats<<<statBlocks, 256, 0, stream>>>(agg1, sums, sumsq, M);
    k_finalize<<<1, 128, 0, stream>>>(sums, sumsq, g1, b1, scale, bias, 1.0f / M);
    k_norm<<<normBlocks, 256, 0, stream>>>(agg1, scale, bias, agg1, total);   // -> x1
    // ---- layer 2 ----
    k_aggBig<<<keyBlocks, 256, 0, stream>>>(agg1, nullptr, r1, offsets, packed, T, nKeys);
    k_gemm384<<<gemmBlocks, 256, 0, stream>>>(T, W2, agg2, M);                 // agg2==agg1
    hipMemsetAsync(sums, 0, 256 * sizeof(float), stream);
    k_stats<<<statBlocks, 256, 0, stream>>>(agg2, sums, sumsq, M);
    k_finalize<<<1, 128, 0, stream>>>(sums, sumsq, g2, b2, scale, bias, 1.0f / M);
    k_norm<<<normBlocks, 256, 0, stream>>>(agg2, scale, bias, agg2, total);   // -> x2
  } else {
    // ---- layer 1 ----
    for (int k = 0; k < 3; ++k) {
      k_aggSmall<<<dstBlocks, 256, 0, stream>>>(ent, ent_ids, rfull, offsets, packed, T, M, k);
      k_gemm128<<<gemmBlocks, 256, 0, stream>>>(T, W1 + (size_t)k * 16384, agg1, M, k == 0);
    }
    hipMemsetAsync(sums, 0, 256 * sizeof(float), stream);
    k_stats<<<statBlocks, 256, 0, stream>>>(agg1, sums, sumsq, M);
    k_finalize<<<1, 128, 0, stream>>>(sums, sumsq, g1, b1, scale, bias, 1.0f / M);
    k_norm<<<normBlocks, 256, 0, stream>>>(agg1, scale, bias, agg1, total);
    // ---- layer 2 ----
    for (int k = 0; k < 3; ++k) {
      k_aggSmall<<<dstBlocks, 256, 0, stream>>>(agg1, nullptr, r1, offsets, packed, T, M, k);
      k_gemm128<<<gemmBlocks, 256, 0, stream>>>(T, W2 + (size_t)k * 16384, agg2, M, k == 0);
    }
    hipMemsetAsync(sums, 0, 256 * sizeof(float), stream);
    k_stats<<<statBlocks, 256, 0, stream>>>(agg2, sums, sumsq, M);
    k_finalize<<<1, 128, 0, stream>>>(sums, sumsq, g2, b2, scale, bias, 1.0f / M);
    k_norm<<<normBlocks, 256, 0, stream>>>(agg2, scale, bias, agg2, total);
  }

  // ---- scoring ----
  k_score<<<(nT * 64 + 255) / 256, 256, 0, stream>>>(agg2, r2, triples, out, nT);
}

// Round 8
// 667.259 us; speedup vs baseline: 2.4754x; 1.4455x over previous
//
#include <hip/hip_runtime.h>
#include <cstdint>

typedef __attribute__((ext_vector_type(8))) short short8;
typedef __attribute__((ext_vector_type(4))) float f32x4;

static __device__ __forceinline__ unsigned short f2bf(float f) {
  unsigned int u = __float_as_uint(f);
  unsigned int r = (u + 0x7FFFu + ((u >> 16) & 1u)) >> 16;   // RNE
  return (unsigned short)r;
}

// r_full[401][128]: rows 0..199 = coeff@bases, 200..399 = -(coeff@bases), 400 = self_rel
__global__ void k_rfull(const float* __restrict__ coeff, const float* __restrict__ bases,
                        const float* __restrict__ selfr, float* __restrict__ rfull) {
  int row = blockIdx.x, c = threadIdx.x;
  float v;
  if (row == 400) {
    v = selfr[c];
  } else {
    int rr = row < 200 ? row : row - 200;
    float s = 0.f;
#pragma unroll 10
    for (int b = 0; b < 50; ++b) s += coeff[rr * 50 + b] * bases[b * 128 + c];
    v = (row < 200) ? s : -s;
  }
  rfull[row * 128 + c] = v;
}

// out[r][c] = sum_k A[r][k]*B[k][c], K=128, N=128 (relation chain)
__global__ void k_rmm(const float* __restrict__ A, const float* __restrict__ B,
                      float* __restrict__ out) {
  int r = blockIdx.x, c = threadIdx.x;
  float s = 0.f;
#pragma unroll 8
  for (int k = 0; k < 128; ++k) s += A[r * 128 + k] * B[k * 128 + c];
  out[r * 128 + c] = s;
}

// WT[n][k] (bf16, k = kk*128+kr) = W[kk][kr][n]  (transposed concat for MFMA B-frags)
__global__ void k_wconv(const float* __restrict__ W, unsigned short* __restrict__ WT) {
  int idx = blockIdx.x * blockDim.x + threadIdx.x;
  if (idx >= 128 * 384) return;
  int n = idx & 127, k = idx >> 7;
  int kk = k >> 7, kr = k & 127;
  WT[(size_t)n * 384 + k] = f2bf(W[(size_t)kk * 16384 + kr * 128 + n]);
}

// ---- CSR build over (dst, class) keys ----
__global__ void k_hist(const int* __restrict__ ei, const int* __restrict__ y,
                       int* __restrict__ counts, int nE) {
  int e = blockIdx.x * blockDim.x + threadIdx.x;
  if (e >= nE) return;
  int dst = ei[nE + e], k = y[e];
  atomicAdd(&counts[dst * 3 + k], 1);
}

__global__ void k_scan1(const int* __restrict__ counts, int* __restrict__ local,
                        int* __restrict__ blockSums, int n) {
  __shared__ int sdata[1024];
  int tid = threadIdx.x;
  int i = blockIdx.x * 1024 + tid;
  int v = (i < n) ? counts[i] : 0;
  sdata[tid] = v;
  __syncthreads();
  for (int off = 1; off < 1024; off <<= 1) {
    int t = (tid >= off) ? sdata[tid - off] : 0;
    __syncthreads();
    sdata[tid] += t;
    __syncthreads();
  }
  if (i < n) local[i] = sdata[tid] - v;
  if (tid == 1023) blockSums[blockIdx.x] = sdata[1023];
}

__global__ void k_scan2(const int* __restrict__ blockSums, int* __restrict__ carries,
                        int* __restrict__ offsets, int n, int nb) {
  __shared__ int sdata[1024];
  int tid = threadIdx.x;
  int v = (tid < nb) ? blockSums[tid] : 0;
  sdata[tid] = v;
  __syncthreads();
  for (int off = 1; off < 1024; off <<= 1) {
    int t = (tid >= off) ? sdata[tid - off] : 0;
    __syncthreads();
    sdata[tid] += t;
    __syncthreads();
  }
  if (tid < nb) carries[tid] = sdata[tid] - v;
  if (tid == 1023) offsets[n] = sdata[1023];
}

__global__ void k_scan3(const int* __restrict__ local, const int* __restrict__ carries,
                        int* __restrict__ offsets, int* __restrict__ cursor, int n) {
  int i = blockIdx.x * 1024 + threadIdx.x;
  if (i >= n) return;
  int v = local[i] + carries[blockIdx.x];
  offsets[i] = v;
  cursor[i] = v;
}

// fill: packed[slot] = src | (type<<20)  (src<2^20, type<=400<2^12)
__global__ void k_fill(const int* __restrict__ ei, const int* __restrict__ et,
                       const int* __restrict__ y, int* __restrict__ cursor,
                       unsigned int* __restrict__ packed, int nE) {
  int e = blockIdx.x * blockDim.x + threadIdx.x;
  if (e >= nE) return;
  int dst = ei[nE + e], k = y[e];
  int slot = atomicAdd(&cursor[dst * 3 + k], 1);
  packed[slot] = (unsigned int)ei[e] | ((unsigned int)et[e] << 20);
}

// gather-aggregate, wave per (dst,class) key, 4 waves/block; bf16 output T[dst*384+k*128+c]
__global__ __launch_bounds__(256) void k_aggBig(const float* __restrict__ x, const int* __restrict__ ids,
                                                const float* __restrict__ r,
                                                const int* __restrict__ offsets,
                                                const unsigned int* __restrict__ packed,
                                                unsigned short* __restrict__ T, int nKeys) {
  int key = blockIdx.x * 4 + (threadIdx.x >> 6);
  if (key >= nKeys) return;
  int lane = threadIdx.x & 63;
  int c = lane * 2;
  int dst = key / 3, k = key - dst * 3;
  int s = offsets[key], e = offsets[key + 1];
  float ax0 = 0.f, ay0 = 0.f, ax1 = 0.f, ay1 = 0.f;
  int j = s;
  for (; j + 1 < e; j += 2) {
    unsigned int p0 = packed[j], p1 = packed[j + 1];
    int s0 = p0 & 0xFFFFF, t0 = p0 >> 20;
    int s1 = p1 & 0xFFFFF, t1 = p1 >> 20;
    if (ids) { s0 = ids[s0]; s1 = ids[s1]; }
    float2 h0 = *(const float2*)&x[(size_t)s0 * 128 + c];
    float2 r0 = *(const float2*)&r[(size_t)t0 * 128 + c];
    float2 h1 = *(const float2*)&x[(size_t)s1 * 128 + c];
    float2 r1 = *(const float2*)&r[(size_t)t1 * 128 + c];
    ax0 += h0.x - r0.x; ay0 += h0.y - r0.y;
    ax1 += h1.x - r1.x; ay1 += h1.y - r1.y;
  }
  if (j < e) {
    unsigned int p0 = packed[j];
    int s0 = p0 & 0xFFFFF, t0 = p0 >> 20;
    if (ids) s0 = ids[s0];
    float2 h0 = *(const float2*)&x[(size_t)s0 * 128 + c];
    float2 r0 = *(const float2*)&r[(size_t)t0 * 128 + c];
    ax0 += h0.x - r0.x; ay0 += h0.y - r0.y;
  }
  unsigned int pk = (unsigned int)f2bf(ax0 + ax1) | ((unsigned int)f2bf(ay0 + ay1) << 16);
  *(unsigned int*)&T[(size_t)dst * 384 + k * 128 + c] = pk;
}

// C[M x 128] = A[M x 384](bf16) @ WT^T (WT is 128x384 bf16, row n = col n of W).
// MFMA 16x16x32 bf16; BM=128, BN=128, BK=32; 4 waves (2x2), 64x64 each.
__global__ __launch_bounds__(256) void k_gemm_mfma(const unsigned short* __restrict__ A,
                                                   const unsigned short* __restrict__ WT,
                                                   float* __restrict__ C, int M) {
  __shared__ unsigned short As[128][40];   // 80B row stride: 16B-aligned, <=2-way banks
  __shared__ unsigned short Bs[128][40];
  const int tid = threadIdx.x;
  const int m0 = blockIdx.x * 128;
  const int wave = tid >> 6, lane = tid & 63;
  const int wrow = wave >> 1, wcol = wave & 1;
  const int quad = lane >> 4, l16 = lane & 15;
  f32x4 acc[4][4] = {};

  for (int kb = 0; kb < 384; kb += 32) {
#pragma unroll
    for (int j = 0; j < 2; ++j) {          // A tile: 128 rows x 32 k
      int idx = tid + 256 * j;
      int rr = idx >> 2, kc = (idx & 3) * 8;
      int m = m0 + rr;
      float4 v = make_float4(0.f, 0.f, 0.f, 0.f);
      if (m < M) v = *(const float4*)&A[(size_t)m * 384 + kb + kc];
      *(float4*)&As[rr][kc] = v;
    }
#pragma unroll
    for (int j = 0; j < 2; ++j) {          // B tile: 128 n-rows x 32 k
      int idx = tid + 256 * j;
      int nn = idx >> 2, kc = (idx & 3) * 8;
      *(float4*)&Bs[nn][kc] = *(const float4*)&WT[(size_t)nn * 384 + kb + kc];
    }
    __syncthreads();
    short8 a[4], b[4];
#pragma unroll
    for (int t = 0; t < 4; ++t) a[t] = *(const short8*)&As[wrow * 64 + t * 16 + l16][quad * 8];
#pragma unroll
    for (int t = 0; t < 4; ++t) b[t] = *(const short8*)&Bs[wcol * 64 + t * 16 + l16][quad * 8];
#pragma unroll
    for (int rt = 0; rt < 4; ++rt)
#pragma unroll
      for (int ct = 0; ct < 4; ++ct)
        acc[rt][ct] = __builtin_amdgcn_mfma_f32_16x16x32_bf16(a[rt], b[ct], acc[rt][ct], 0, 0, 0);
    __syncthreads();
  }
  // C/D layout: col = lane&15, row = quad*4 + reg
#pragma unroll
  for (int rt = 0; rt < 4; ++rt) {
#pragma unroll
    for (int reg = 0; reg < 4; ++reg) {
      int m = m0 + wrow * 64 + rt * 16 + quad * 4 + reg;
      if (m < M) {
#pragma unroll
        for (int ct = 0; ct < 4; ++ct) {
          int col = wcol * 64 + ct * 16 + l16;
          C[(size_t)m * 128 + col] = acc[rt][ct][reg];
        }
      }
    }
  }
}

// per-column sum & sumsq over rows
__global__ void k_stats(const float* __restrict__ agg, float* __restrict__ sums,
                        float* __restrict__ sumsq, int M) {
  int c = threadIdx.x & 127;
  int g = threadIdx.x >> 7;
  int row0 = blockIdx.x * 256;
  int rend = min(row0 + 256, M);
  float s = 0.f, q = 0.f;
  for (int r = row0 + g; r < rend; r += 2) {
    float v = agg[(size_t)r * 128 + c];
    s += v; q += v * v;
  }
  atomicAdd(&sums[c], s);
  atomicAdd(&sumsq[c], q);
}

__global__ void k_finalize(const float* __restrict__ sums, const float* __restrict__ sumsq,
                           const float* __restrict__ gamma, const float* __restrict__ beta,
                           float* __restrict__ scale, float* __restrict__ bias, float invN) {
  int c = threadIdx.x;
  float mean = sums[c] * invN;
  float var = fmaxf(sumsq[c] * invN - mean * mean, 0.f);
  float sc = rsqrtf(var + 1e-5f) * gamma[c];
  scale[c] = sc;
  bias[c] = beta[c] - mean * sc;
}

__global__ void k_norm(const float* __restrict__ agg, const float* __restrict__ scale,
                       const float* __restrict__ bias, float* __restrict__ x, int total) {
  int idx = blockIdx.x * blockDim.x + threadIdx.x;
  if (idx >= total) return;
  int c = idx & 127;
  x[idx] = tanhf(fmaf(agg[idx], scale[c], bias[c]));
}

// one wave per triple: sum_d |x[h]+r[rel]-x[t]|
__global__ void k_score(const float* __restrict__ x, const float* __restrict__ r,
                        const int* __restrict__ triples, float* __restrict__ out, int nT) {
  int gid = blockIdx.x * blockDim.x + threadIdx.x;
  int t = gid >> 6;
  if (t >= nT) return;
  int lane = gid & 63;
  int h = triples[t * 3], rel = triples[t * 3 + 1], tl = triples[t * 3 + 2];
  int d = lane * 2;
  float2 a = *(const float2*)&x[(size_t)h * 128 + d];
  float2 b = *(const float2*)&r[(size_t)rel * 128 + d];
  float2 cc = *(const float2*)&x[(size_t)tl * 128 + d];
  float s = fabsf(a.x + b.x - cc.x) + fabsf(a.y + b.y - cc.y);
#pragma unroll
  for (int off = 32; off > 0; off >>= 1) s += __shfl_down(s, off);
  if (lane == 0) out[t] = s;
}

extern "C" void kernel_launch(void* const* d_in, const int* in_sizes, int n_in,
                              void* d_out, int out_size, void* d_ws, size_t ws_size,
                              hipStream_t stream) {
  const float* ent   = (const float*)d_in[0];
  const float* bases = (const float*)d_in[1];
  const float* coeff = (const float*)d_in[2];
  const float* selfr = (const float*)d_in[3];
  const float* W1    = (const float*)d_in[4];
  const float* relw1 = (const float*)d_in[5];
  const float* g1    = (const float*)d_in[6];
  const float* b1    = (const float*)d_in[7];
  const float* W2    = (const float*)d_in[8];
  const float* relw2 = (const float*)d_in[9];
  const float* g2    = (const float*)d_in[10];
  const float* b2    = (const float*)d_in[11];
  const int* ent_ids = (const int*)d_in[12];
  const int* ei      = (const int*)d_in[13];
  const int* et      = (const int*)d_in[14];
  const int* yk      = (const int*)d_in[15];
  const int* triples = (const int*)d_in[16];

  const int M  = in_sizes[0] / 128;   // 100000
  const int nE = in_sizes[14];        // 800000
  const int nT = in_sizes[16] / 3;    // 4096
  const int nKeys = M * 3;
  const int nScanBlocks = (nKeys + 1023) / 1024;

  // workspace layout (~137 MB)
  float* p = (float*)d_ws;
  float* rfull = p; p += 401 * 128;
  float* r1    = p; p += 401 * 128;
  float* r2    = p; p += 401 * 128;
  float* sums  = p; p += 128;
  float* sumsq = p; p += 128;
  float* scale = p; p += 128;
  float* bias  = p; p += 128;
  float* agg1  = p; p += (size_t)M * 128;            // layer outputs (x1, then x2 in-place)
  unsigned short* T   = (unsigned short*)p;          // M*384 bf16
  unsigned short* WT1 = T + (size_t)M * 384;         // 128*384 bf16
  unsigned short* WT2 = WT1 + 128 * 384;
  int* counts  = (int*)(WT2 + 128 * 384);
  int* offsets = counts + nKeys;
  int* cursor  = offsets + nKeys + 1;
  int* slocal  = cursor + nKeys;
  int* sblock  = slocal + nKeys;
  int* scarry  = sblock + nScanBlocks;
  unsigned int* packed = (unsigned int*)(scarry + nScanBlocks);

  float* out = (float*)d_out;

  const int mfmaBlocks = (M + 127) / 128;
  const int statBlocks = (M + 255) / 256;
  const int total = M * 128;
  const int normBlocks = (total + 255) / 256;
  const int edgeBlocks = (nE + 255) / 256;
  const int keyBlocks  = (nKeys + 3) / 4;

  // relation chain + weight conversion
  k_rfull<<<401, 128, 0, stream>>>(coeff, bases, selfr, rfull);
  k_rmm<<<401, 128, 0, stream>>>(rfull, relw1, r1);
  k_rmm<<<401, 128, 0, stream>>>(r1, relw2, r2);
  k_wconv<<<192, 256, 0, stream>>>(W1, WT1);
  k_wconv<<<192, 256, 0, stream>>>(W2, WT2);

  // CSR over (dst, class) with packed (src|type<<20) payload
  hipMemsetAsync(counts, 0, (size_t)nKeys * sizeof(int), stream);
  k_hist<<<edgeBlocks, 256, 0, stream>>>(ei, yk, counts, nE);
  k_scan1<<<nScanBlocks, 1024, 0, stream>>>(counts, slocal, sblock, nKeys);
  k_scan2<<<1, 1024, 0, stream>>>(sblock, scarry, offsets, nKeys, nScanBlocks);
  k_scan3<<<nScanBlocks, 1024, 0, stream>>>(slocal, scarry, offsets, cursor, nKeys);
  k_fill<<<edgeBlocks, 256, 0, stream>>>(ei, et, yk, cursor, packed, nE);

  // ---- layer 1 ----
  k_aggBig<<<keyBlocks, 256, 0, stream>>>(ent, ent_ids, rfull, offsets, packed, T, nKeys);
  k_gemm_mfma<<<mfmaBlocks, 256, 0, stream>>>(T, WT1, agg1, M);
  hipMemsetAsync(sums, 0, 256 * sizeof(float), stream);
  k_stats<<<statBlocks, 256, 0, stream>>>(agg1, sums, sumsq, M);
  k_finalize<<<1, 128, 0, stream>>>(sums, sumsq, g1, b1, scale, bias, 1.0f / M);
  k_norm<<<normBlocks, 256, 0, stream>>>(agg1, scale, bias, agg1, total);   // -> x1

  // ---- layer 2 ----
  k_aggBig<<<keyBlocks, 256, 0, stream>>>(agg1, nullptr, r1, offsets, packed, T, nKeys);
  k_gemm_mfma<<<mfmaBlocks, 256, 0, stream>>>(T, WT2, agg1, M);
  hipMemsetAsync(sums, 0, 256 * sizeof(float), stream);
  k_stats<<<statBlocks, 256, 0, stream>>>(agg1, sums, sumsq, M);
  k_finalize<<<1, 128, 0, stream>>>(sums, sumsq, g2, b2, scale, bias, 1.0f / M);
  k_norm<<<normBlocks, 256, 0, stream>>>(agg1, scale, bias, agg1, total);   // -> x2

  // ---- scoring ----
  k_score<<<(nT * 64 + 255) / 256, 256, 0, stream>>>(agg1, r2, triples, out, nT);
}

// Round 9
// 639.125 us; speedup vs baseline: 2.5844x; 1.0440x over previous
//
#include <hip/hip_runtime.h>
#include <cstdint>

typedef __attribute__((ext_vector_type(8))) short short8;
typedef __attribute__((ext_vector_type(4))) float f32x4;

static __device__ __forceinline__ unsigned short f2bf(float f) {
  unsigned int u = __float_as_uint(f);
  unsigned int r = (u + 0x7FFFu + ((u >> 16) & 1u)) >> 16;   // RNE
  return (unsigned short)r;
}
static __device__ __forceinline__ unsigned int pack2bf(float a, float b) {
  return (unsigned int)f2bf(a) | ((unsigned int)f2bf(b) << 16);
}
static __device__ __forceinline__ float2 bf2f(unsigned int u) {
  return make_float2(__uint_as_float(u << 16), __uint_as_float(u & 0xFFFF0000u));
}

// r_full[401][128]: rows 0..199 = coeff@bases, 200..399 = -(coeff@bases), 400 = self_rel
__global__ void k_rfull(const float* __restrict__ coeff, const float* __restrict__ bases,
                        const float* __restrict__ selfr, float* __restrict__ rfull) {
  int row = blockIdx.x, c = threadIdx.x;
  float v;
  if (row == 400) {
    v = selfr[c];
  } else {
    int rr = row < 200 ? row : row - 200;
    float s = 0.f;
#pragma unroll 10
    for (int b = 0; b < 50; ++b) s += coeff[rr * 50 + b] * bases[b * 128 + c];
    v = (row < 200) ? s : -s;
  }
  rfull[row * 128 + c] = v;
}

// out[r][c] = sum_k A[r][k]*B[k][c], K=128, N=128 (relation chain)
__global__ void k_rmm(const float* __restrict__ A, const float* __restrict__ B,
                      float* __restrict__ out) {
  int r = blockIdx.x, c = threadIdx.x;
  float s = 0.f;
#pragma unroll 8
  for (int k = 0; k < 128; ++k) s += A[r * 128 + k] * B[k * 128 + c];
  out[r * 128 + c] = s;
}

// convert fp32 table (nRows x 128) -> packed bf16-pair table (nRows x 64 uints)
__global__ void k_cvt(const float* __restrict__ src, unsigned int* __restrict__ dst, int nPairs) {
  int i = blockIdx.x * blockDim.x + threadIdx.x;
  if (i >= nPairs) return;
  float2 v = *(const float2*)&src[(size_t)i * 2];
  dst[i] = pack2bf(v.x, v.y);
}

// WT[n][k] (bf16, k = kk*128+kr) = W[kk][kr][n]  (transposed concat for MFMA B-frags)
__global__ void k_wconv(const float* __restrict__ W, unsigned short* __restrict__ WT) {
  int idx = blockIdx.x * blockDim.x + threadIdx.x;
  if (idx >= 128 * 384) return;
  int n = idx & 127, k = idx >> 7;
  int kk = k >> 7, kr = k & 127;
  WT[(size_t)n * 384 + k] = f2bf(W[(size_t)kk * 16384 + kr * 128 + n]);
}

// ---- CSR build over (dst, class) keys ----
__global__ void k_hist(const int* __restrict__ ei, const int* __restrict__ y,
                       int* __restrict__ counts, int nE) {
  int e = blockIdx.x * blockDim.x + threadIdx.x;
  if (e >= nE) return;
  int dst = ei[nE + e], k = y[e];
  atomicAdd(&counts[dst * 3 + k], 1);
}

__global__ void k_scan1(const int* __restrict__ counts, int* __restrict__ local,
                        int* __restrict__ blockSums, int n) {
  __shared__ int sdata[1024];
  int tid = threadIdx.x;
  int i = blockIdx.x * 1024 + tid;
  int v = (i < n) ? counts[i] : 0;
  sdata[tid] = v;
  __syncthreads();
  for (int off = 1; off < 1024; off <<= 1) {
    int t = (tid >= off) ? sdata[tid - off] : 0;
    __syncthreads();
    sdata[tid] += t;
    __syncthreads();
  }
  if (i < n) local[i] = sdata[tid] - v;
  if (tid == 1023) blockSums[blockIdx.x] = sdata[1023];
}

__global__ void k_scan2(const int* __restrict__ blockSums, int* __restrict__ carries,
                        int* __restrict__ offsets, int n, int nb) {
  __shared__ int sdata[1024];
  int tid = threadIdx.x;
  int v = (tid < nb) ? blockSums[tid] : 0;
  sdata[tid] = v;
  __syncthreads();
  for (int off = 1; off < 1024; off <<= 1) {
    int t = (tid >= off) ? sdata[tid - off] : 0;
    __syncthreads();
    sdata[tid] += t;
    __syncthreads();
  }
  if (tid < nb) carries[tid] = sdata[tid] - v;
  if (tid == 1023) offsets[n] = sdata[1023];
}

__global__ void k_scan3(const int* __restrict__ local, const int* __restrict__ carries,
                        int* __restrict__ offsets, int* __restrict__ cursor, int n) {
  int i = blockIdx.x * 1024 + threadIdx.x;
  if (i >= n) return;
  int v = local[i] + carries[blockIdx.x];
  offsets[i] = v;
  cursor[i] = v;
}

// fill: packed[slot] = src | (type<<20)  (src<2^20, type<=400<2^12)
__global__ void k_fill(const int* __restrict__ ei, const int* __restrict__ et,
                       const int* __restrict__ y, int* __restrict__ cursor,
                       unsigned int* __restrict__ packed, int nE) {
  int e = blockIdx.x * blockDim.x + threadIdx.x;
  if (e >= nE) return;
  int dst = ei[nE + e], k = y[e];
  int slot = atomicAdd(&cursor[dst * 3 + k], 1);
  packed[slot] = (unsigned int)ei[e] | ((unsigned int)et[e] << 20);
}

// gather-aggregate from PACKED-BF16 tables; wave per (dst,class) key, 4 waves/block.
// xb: M x 64 uints (bf16 pairs), rb: 401 x 64 uints. Output T bf16 [dst*384 + k*128 + c].
__global__ __launch_bounds__(256) void k_aggBig(const unsigned int* __restrict__ xb,
                                                const int* __restrict__ ids,
                                                const unsigned int* __restrict__ rb,
                                                const int* __restrict__ offsets,
                                                const unsigned int* __restrict__ packed,
                                                unsigned short* __restrict__ T, int nKeys) {
  int key = blockIdx.x * 4 + (threadIdx.x >> 6);
  if (key >= nKeys) return;
  int lane = threadIdx.x & 63;
  int dst = key / 3, k = key - dst * 3;
  int s = offsets[key], e = offsets[key + 1];
  float ax0 = 0.f, ay0 = 0.f, ax1 = 0.f, ay1 = 0.f;
  int j = s;
  for (; j + 1 < e; j += 2) {
    unsigned int p0 = packed[j], p1 = packed[j + 1];
    int s0 = p0 & 0xFFFFF, t0 = p0 >> 20;
    int s1 = p1 & 0xFFFFF, t1 = p1 >> 20;
    if (ids) { s0 = ids[s0]; s1 = ids[s1]; }
    float2 h0 = bf2f(xb[(size_t)s0 * 64 + lane]);
    float2 r0 = bf2f(rb[(size_t)t0 * 64 + lane]);
    float2 h1 = bf2f(xb[(size_t)s1 * 64 + lane]);
    float2 r1 = bf2f(rb[(size_t)t1 * 64 + lane]);
    ax0 += h0.x - r0.x; ay0 += h0.y - r0.y;
    ax1 += h1.x - r1.x; ay1 += h1.y - r1.y;
  }
  if (j < e) {
    unsigned int p0 = packed[j];
    int s0 = p0 & 0xFFFFF, t0 = p0 >> 20;
    if (ids) s0 = ids[s0];
    float2 h0 = bf2f(xb[(size_t)s0 * 64 + lane]);
    float2 r0 = bf2f(rb[(size_t)t0 * 64 + lane]);
    ax0 += h0.x - r0.x; ay0 += h0.y - r0.y;
  }
  unsigned int pk = pack2bf(ax0 + ax1, ay0 + ay1);
  *(unsigned int*)&T[(size_t)dst * 384 + k * 128 + lane * 2] = pk;
}

// C[M x 128] = A[M x 384](bf16) @ WT^T (WT is 128x384 bf16, row n = col n of W).
// MFMA 16x16x32 bf16; BM=128, BN=128, BK=32; 4 waves (2x2), 64x64 each.
__global__ __launch_bounds__(256) void k_gemm_mfma(const unsigned short* __restrict__ A,
                                                   const unsigned short* __restrict__ WT,
                                                   float* __restrict__ C, int M) {
  __shared__ unsigned short As[128][40];   // 80B row stride
  __shared__ unsigned short Bs[128][40];
  const int tid = threadIdx.x;
  const int m0 = blockIdx.x * 128;
  const int wave = tid >> 6, lane = tid & 63;
  const int wrow = wave >> 1, wcol = wave & 1;
  const int quad = lane >> 4, l16 = lane & 15;
  f32x4 acc[4][4] = {};

  for (int kb = 0; kb < 384; kb += 32) {
#pragma unroll
    for (int j = 0; j < 2; ++j) {          // A tile: 128 rows x 32 k
      int idx = tid + 256 * j;
      int rr = idx >> 2, kc = (idx & 3) * 8;
      int m = m0 + rr;
      float4 v = make_float4(0.f, 0.f, 0.f, 0.f);
      if (m < M) v = *(const float4*)&A[(size_t)m * 384 + kb + kc];
      *(float4*)&As[rr][kc] = v;
    }
#pragma unroll
    for (int j = 0; j < 2; ++j) {          // B tile: 128 n-rows x 32 k
      int idx = tid + 256 * j;
      int nn = idx >> 2, kc = (idx & 3) * 8;
      *(float4*)&Bs[nn][kc] = *(const float4*)&WT[(size_t)nn * 384 + kb + kc];
    }
    __syncthreads();
    short8 a[4], b[4];
#pragma unroll
    for (int t = 0; t < 4; ++t) a[t] = *(const short8*)&As[wrow * 64 + t * 16 + l16][quad * 8];
#pragma unroll
    for (int t = 0; t < 4; ++t) b[t] = *(const short8*)&Bs[wcol * 64 + t * 16 + l16][quad * 8];
#pragma unroll
    for (int rt = 0; rt < 4; ++rt)
#pragma unroll
      for (int ct = 0; ct < 4; ++ct)
        acc[rt][ct] = __builtin_amdgcn_mfma_f32_16x16x32_bf16(a[rt], b[ct], acc[rt][ct], 0, 0, 0);
    __syncthreads();
  }
#pragma unroll
  for (int rt = 0; rt < 4; ++rt) {
#pragma unroll
    for (int reg = 0; reg < 4; ++reg) {
      int m = m0 + wrow * 64 + rt * 16 + quad * 4 + reg;
      if (m < M) {
#pragma unroll
        for (int ct = 0; ct < 4; ++ct) {
          int col = wcol * 64 + ct * 16 + l16;
          C[(size_t)m * 128 + col] = acc[rt][ct][reg];
        }
      }
    }
  }
}

// per-column sum & sumsq over rows
__global__ void k_stats(const float* __restrict__ agg, float* __restrict__ sums,
                        float* __restrict__ sumsq, int M) {
  int c = threadIdx.x & 127;
  int g = threadIdx.x >> 7;
  int row0 = blockIdx.x * 256;
  int rend = min(row0 + 256, M);
  float s = 0.f, q = 0.f;
  for (int r = row0 + g; r < rend; r += 2) {
    float v = agg[(size_t)r * 128 + c];
    s += v; q += v * v;
  }
  atomicAdd(&sums[c], s);
  atomicAdd(&sumsq[c], q);
}

__global__ void k_finalize(const float* __restrict__ sums, const float* __restrict__ sumsq,
                           const float* __restrict__ gamma, const float* __restrict__ beta,
                           float* __restrict__ scale, float* __restrict__ bias, float invN) {
  int c = threadIdx.x;
  float mean = sums[c] * invN;
  float var = fmaxf(sumsq[c] * invN - mean * mean, 0.f);
  float sc = rsqrtf(var + 1e-5f) * gamma[c];
  scale[c] = sc;
  bias[c] = beta[c] - mean * sc;
}

// norm + tanh, writing ONLY the packed-bf16 x-table (col pair per thread)
__global__ void k_norm(const float* __restrict__ agg, const float* __restrict__ scale,
                       const float* __restrict__ bias, unsigned int* __restrict__ xb, int nPairs) {
  int i = blockIdx.x * blockDim.x + threadIdx.x;
  if (i >= nPairs) return;
  int j = i & 63;
  float2 v = *(const float2*)&agg[(size_t)i * 2];
  float a = tanhf(fmaf(v.x, scale[2 * j], bias[2 * j]));
  float b = tanhf(fmaf(v.y, scale[2 * j + 1], bias[2 * j + 1]));
  xb[i] = pack2bf(a, b);
}

// one wave per triple: sum_d |x[h]+r[rel]-x[t]|; x is packed bf16, r fp32
__global__ void k_score(const unsigned int* __restrict__ xb, const float* __restrict__ r,
                        const int* __restrict__ triples, float* __restrict__ out, int nT) {
  int gid = blockIdx.x * blockDim.x + threadIdx.x;
  int t = gid >> 6;
  if (t >= nT) return;
  int lane = gid & 63;
  int h = triples[t * 3], rel = triples[t * 3 + 1], tl = triples[t * 3 + 2];
  float2 a = bf2f(xb[(size_t)h * 64 + lane]);
  float2 b = *(const float2*)&r[(size_t)rel * 128 + lane * 2];
  float2 cc = bf2f(xb[(size_t)tl * 64 + lane]);
  float s = fabsf(a.x + b.x - cc.x) + fabsf(a.y + b.y - cc.y);
#pragma unroll
  for (int off = 32; off > 0; off >>= 1) s += __shfl_down(s, off);
  if (lane == 0) out[t] = s;
}

extern "C" void kernel_launch(void* const* d_in, const int* in_sizes, int n_in,
                              void* d_out, int out_size, void* d_ws, size_t ws_size,
                              hipStream_t stream) {
  const float* ent   = (const float*)d_in[0];
  const float* bases = (const float*)d_in[1];
  const float* coeff = (const float*)d_in[2];
  const float* selfr = (const float*)d_in[3];
  const float* W1    = (const float*)d_in[4];
  const float* relw1 = (const float*)d_in[5];
  const float* g1    = (const float*)d_in[6];
  const float* b1    = (const float*)d_in[7];
  const float* W2    = (const float*)d_in[8];
  const float* relw2 = (const float*)d_in[9];
  const float* g2    = (const float*)d_in[10];
  const float* b2    = (const float*)d_in[11];
  const int* ent_ids = (const int*)d_in[12];
  const int* ei      = (const int*)d_in[13];
  const int* et      = (const int*)d_in[14];
  const int* yk      = (const int*)d_in[15];
  const int* triples = (const int*)d_in[16];

  const int M  = in_sizes[0] / 128;   // 100000
  const int nE = in_sizes[14];        // 800000
  const int nT = in_sizes[16] / 3;    // 4096
  const int nKeys = M * 3;
  const int nScanBlocks = (nKeys + 1023) / 1024;

  // workspace layout (~162 MB)
  float* p = (float*)d_ws;
  float* rfull = p; p += 401 * 128;
  float* r1    = p; p += 401 * 128;
  float* r2    = p; p += 401 * 128;
  float* sums  = p; p += 128;
  float* sumsq = p; p += 128;
  float* scale = p; p += 128;
  float* bias  = p; p += 128;
  float* agg1  = p; p += (size_t)M * 128;            // GEMM output (fp32)
  unsigned int* entbf = (unsigned int*)agg1;         // alias: ent bf16 lives here pre-GEMM
  unsigned int* xb    = (unsigned int*)p;            // M*64 packed bf16 x-table
  unsigned int* rfb   = xb + (size_t)M * 64;         // 401*64
  unsigned int* r1b   = rfb + 401 * 64;              // 401*64
  unsigned short* T   = (unsigned short*)(r1b + 401 * 64);  // M*384 bf16
  unsigned short* WT1 = T + (size_t)M * 384;
  unsigned short* WT2 = WT1 + 128 * 384;
  int* counts  = (int*)(WT2 + 128 * 384);
  int* offsets = counts + nKeys;
  int* cursor  = offsets + nKeys + 1;
  int* slocal  = cursor + nKeys;
  int* sblock  = slocal + nKeys;
  int* scarry  = sblock + nScanBlocks;
  unsigned int* packed = (unsigned int*)(scarry + nScanBlocks);

  float* out = (float*)d_out;

  const int mfmaBlocks = (M + 127) / 128;
  const int statBlocks = (M + 255) / 256;
  const int nPairs = M * 64;
  const int pairBlocks = (nPairs + 255) / 256;
  const int edgeBlocks = (nE + 255) / 256;
  const int keyBlocks  = (nKeys + 3) / 4;

  // relation chain + conversions
  k_rfull<<<401, 128, 0, stream>>>(coeff, bases, selfr, rfull);
  k_rmm<<<401, 128, 0, stream>>>(rfull, relw1, r1);
  k_rmm<<<401, 128, 0, stream>>>(r1, relw2, r2);
  k_cvt<<<(401 * 64 + 255) / 256, 256, 0, stream>>>(rfull, rfb, 401 * 64);
  k_cvt<<<(401 * 64 + 255) / 256, 256, 0, stream>>>(r1, r1b, 401 * 64);
  k_cvt<<<pairBlocks, 256, 0, stream>>>(ent, entbf, nPairs);
  k_wconv<<<192, 256, 0, stream>>>(W1, WT1);
  k_wconv<<<192, 256, 0, stream>>>(W2, WT2);

  // CSR over (dst, class) with packed (src|type<<20) payload
  hipMemsetAsync(counts, 0, (size_t)nKeys * sizeof(int), stream);
  k_hist<<<edgeBlocks, 256, 0, stream>>>(ei, yk, counts, nE);
  k_scan1<<<nScanBlocks, 1024, 0, stream>>>(counts, slocal, sblock, nKeys);
  k_scan2<<<1, 1024, 0, stream>>>(sblock, scarry, offsets, nKeys, nScanBlocks);
  k_scan3<<<nScanBlocks, 1024, 0, stream>>>(slocal, scarry, offsets, cursor, nKeys);
  k_fill<<<edgeBlocks, 256, 0, stream>>>(ei, et, yk, cursor, packed, nE);

  // ---- layer 1: gather entbf (alias of agg1 — dead before GEMM writes it) ----
  k_aggBig<<<keyBlocks, 256, 0, stream>>>(entbf, ent_ids, rfb, offsets, packed, T, nKeys);
  k_gemm_mfma<<<mfmaBlocks, 256, 0, stream>>>(T, WT1, agg1, M);
  hipMemsetAsync(sums, 0, 256 * sizeof(float), stream);
  k_stats<<<statBlocks, 256, 0, stream>>>(agg1, sums, sumsq, M);
  k_finalize<<<1, 128, 0, stream>>>(sums, sumsq, g1, b1, scale, bias, 1.0f / M);
  k_norm<<<pairBlocks, 256, 0, stream>>>(agg1, scale, bias, xb, nPairs);   // -> x1 (bf16)

  // ---- layer 2 ----
  k_aggBig<<<keyBlocks, 256, 0, stream>>>(xb, nullptr, r1b, offsets, packed, T, nKeys);
  k_gemm_mfma<<<mfmaBlocks, 256, 0, stream>>>(T, WT2, agg1, M);
  hipMemsetAsync(sums, 0, 256 * sizeof(float), stream);
  k_stats<<<statBlocks, 256, 0, stream>>>(agg1, sums, sumsq, M);
  k_finalize<<<1, 128, 0, stream>>>(sums, sumsq, g2, b2, scale, bias, 1.0f / M);
  k_norm<<<pairBlocks, 256, 0, stream>>>(agg1, scale, bias, xb, nPairs);   // -> x2 (bf16)

  // ---- scoring ----
  k_score<<<(nT * 64 + 255) / 256, 256, 0, stream>>>(xb, r2, triples, out, nT);
}

// Round 10
// 492.705 us; speedup vs baseline: 3.3524x; 1.2972x over previous
//
#include <hip/hip_runtime.h>
#include <cstdint>

typedef __attribute__((ext_vector_type(8))) short short8;
typedef __attribute__((ext_vector_type(4))) float f32x4;

static __device__ __forceinline__ unsigned short f2bf(float f) {
  unsigned int u = __float_as_uint(f);
  unsigned int r = (u + 0x7FFFu + ((u >> 16) & 1u)) >> 16;   // RNE
  return (unsigned short)r;
}
static __device__ __forceinline__ unsigned int pack2bf(float a, float b) {
  return (unsigned int)f2bf(a) | ((unsigned int)f2bf(b) << 16);
}
static __device__ __forceinline__ float2 bf2f(unsigned int u) {
  return make_float2(__uint_as_float(u << 16), __uint_as_float(u & 0xFFFF0000u));
}
static __device__ __forceinline__ void acc8(float* a, uint4 h, uint4 r) {
  float2 f, g;
  f = bf2f(h.x); g = bf2f(r.x); a[0] += f.x - g.x; a[1] += f.y - g.y;
  f = bf2f(h.y); g = bf2f(r.y); a[2] += f.x - g.x; a[3] += f.y - g.y;
  f = bf2f(h.z); g = bf2f(r.z); a[4] += f.x - g.x; a[5] += f.y - g.y;
  f = bf2f(h.w); g = bf2f(r.w); a[6] += f.x - g.x; a[7] += f.y - g.y;
}

// r_full[401][128] fp32 + packed bf16 copy
__global__ void k_rfull(const float* __restrict__ coeff, const float* __restrict__ bases,
                        const float* __restrict__ selfr, float* __restrict__ rfull,
                        unsigned int* __restrict__ rfb) {
  __shared__ float row_s[128];
  int row = blockIdx.x, c = threadIdx.x;
  float v;
  if (row == 400) {
    v = selfr[c];
  } else {
    int rr = row < 200 ? row : row - 200;
    float s = 0.f;
#pragma unroll 10
    for (int b = 0; b < 50; ++b) s += coeff[rr * 50 + b] * bases[b * 128 + c];
    v = (row < 200) ? s : -s;
  }
  rfull[row * 128 + c] = v;
  row_s[c] = v;
  __syncthreads();
  if (c < 64) rfb[row * 64 + c] = pack2bf(row_s[2 * c], row_s[2 * c + 1]);
}

// out[r][c] = sum_k A[r][k]*B[k][c], K=128, N=128; optional packed bf16 copy
__global__ void k_rmm(const float* __restrict__ A, const float* __restrict__ B,
                      float* __restrict__ out, unsigned int* __restrict__ outb) {
  __shared__ float row_s[128];
  int r = blockIdx.x, c = threadIdx.x;
  float s = 0.f;
#pragma unroll 8
  for (int k = 0; k < 128; ++k) s += A[r * 128 + k] * B[k * 128 + c];
  out[r * 128 + c] = s;
  if (outb) {
    row_s[c] = s;
    __syncthreads();
    if (c < 64) outb[r * 64 + c] = pack2bf(row_s[2 * c], row_s[2 * c + 1]);
  }
}

// convert fp32 table -> packed bf16-pair table
__global__ void k_cvt(const float* __restrict__ src, unsigned int* __restrict__ dst, int nPairs) {
  int i = blockIdx.x * blockDim.x + threadIdx.x;
  if (i >= nPairs) return;
  float2 v = *(const float2*)&src[(size_t)i * 2];
  dst[i] = pack2bf(v.x, v.y);
}

// WT[n][k] (bf16, k = kk*128+kr) = W[kk][kr][n]
__global__ void k_wconv(const float* __restrict__ W, unsigned short* __restrict__ WT) {
  int idx = blockIdx.x * blockDim.x + threadIdx.x;
  if (idx >= 128 * 384) return;
  int n = idx & 127, k = idx >> 7;
  int kk = k >> 7, kr = k & 127;
  WT[(size_t)n * 384 + k] = f2bf(W[(size_t)kk * 16384 + kr * 128 + n]);
}

// ---- CSR build over (dst, class) keys ----
__global__ void k_hist(const int* __restrict__ ei, const int* __restrict__ y,
                       int* __restrict__ counts, int nE) {
  int e = blockIdx.x * blockDim.x + threadIdx.x;
  if (e >= nE) return;
  int dst = ei[nE + e], k = y[e];
  atomicAdd(&counts[dst * 3 + k], 1);
}

__global__ void k_scan1(const int* __restrict__ counts, int* __restrict__ local,
                        int* __restrict__ blockSums, int n) {
  __shared__ int sdata[1024];
  int tid = threadIdx.x;
  int i = blockIdx.x * 1024 + tid;
  int v = (i < n) ? counts[i] : 0;
  sdata[tid] = v;
  __syncthreads();
  for (int off = 1; off < 1024; off <<= 1) {
    int t = (tid >= off) ? sdata[tid - off] : 0;
    __syncthreads();
    sdata[tid] += t;
    __syncthreads();
  }
  if (i < n) local[i] = sdata[tid] - v;
  if (tid == 1023) blockSums[blockIdx.x] = sdata[1023];
}

__global__ void k_scan2(const int* __restrict__ blockSums, int* __restrict__ carries,
                        int* __restrict__ offsets, int n, int nb) {
  __shared__ int sdata[1024];
  int tid = threadIdx.x;
  int v = (tid < nb) ? blockSums[tid] : 0;
  sdata[tid] = v;
  __syncthreads();
  for (int off = 1; off < 1024; off <<= 1) {
    int t = (tid >= off) ? sdata[tid - off] : 0;
    __syncthreads();
    sdata[tid] += t;
    __syncthreads();
  }
  if (tid < nb) carries[tid] = sdata[tid] - v;
  if (tid == 1023) offsets[n] = sdata[1023];
}

__global__ void k_scan3(const int* __restrict__ local, const int* __restrict__ carries,
                        int* __restrict__ offsets, int* __restrict__ cursor, int n) {
  int i = blockIdx.x * 1024 + threadIdx.x;
  if (i >= n) return;
  int v = local[i] + carries[blockIdx.x];
  offsets[i] = v;
  cursor[i] = v;
}

// fill: packed[slot] = src | (type<<20)
__global__ void k_fill(const int* __restrict__ ei, const int* __restrict__ et,
                       const int* __restrict__ y, int* __restrict__ cursor,
                       unsigned int* __restrict__ packed, int nE) {
  int e = blockIdx.x * blockDim.x + threadIdx.x;
  if (e >= nE) return;
  int dst = ei[nE + e], k = y[e];
  int slot = atomicAdd(&cursor[dst * 3 + k], 1);
  packed[slot] = (unsigned int)ei[e] | ((unsigned int)et[e] << 20);
}

// gather-aggregate: 4 keys per wave (16 lanes/key), uint4 (16B) loads, 2-edge unroll.
// xb: M x 64 uints (bf16 pairs); rb: 401 x 64. T bf16 out [dst*384 + k*128 + :]
__global__ __launch_bounds__(256) void k_agg4(const unsigned int* __restrict__ xb,
                                              const int* __restrict__ ids,
                                              const unsigned int* __restrict__ rb,
                                              const int* __restrict__ offsets,
                                              const unsigned int* __restrict__ packed,
                                              unsigned short* __restrict__ T, int nKeys) {
  int wid = blockIdx.x * 4 + (threadIdx.x >> 6);
  int lane = threadIdx.x & 63;
  int quad = lane >> 4, l16 = lane & 15;
  int key = wid * 4 + quad;
  if (key >= nKeys) return;
  int dst = key / 3, k = key - dst * 3;
  int s = offsets[key], e = offsets[key + 1];
  float a0[8] = {}, a1[8] = {};
  int j = s;
  for (; j + 1 < e; j += 2) {
    unsigned int p0 = packed[j], p1 = packed[j + 1];
    int s0 = p0 & 0xFFFFF, t0 = p0 >> 20;
    int s1 = p1 & 0xFFFFF, t1 = p1 >> 20;
    if (ids) { s0 = ids[s0]; s1 = ids[s1]; }
    uint4 h0 = *(const uint4*)&xb[(size_t)s0 * 64 + l16 * 4];
    uint4 r0 = *(const uint4*)&rb[(size_t)t0 * 64 + l16 * 4];
    uint4 h1 = *(const uint4*)&xb[(size_t)s1 * 64 + l16 * 4];
    uint4 r1 = *(const uint4*)&rb[(size_t)t1 * 64 + l16 * 4];
    acc8(a0, h0, r0);
    acc8(a1, h1, r1);
  }
  if (j < e) {
    unsigned int p0 = packed[j];
    int s0 = p0 & 0xFFFFF, t0 = p0 >> 20;
    if (ids) s0 = ids[s0];
    uint4 h0 = *(const uint4*)&xb[(size_t)s0 * 64 + l16 * 4];
    uint4 r0 = *(const uint4*)&rb[(size_t)t0 * 64 + l16 * 4];
    acc8(a0, h0, r0);
  }
  uint4 o;
  o.x = pack2bf(a0[0] + a1[0], a0[1] + a1[1]);
  o.y = pack2bf(a0[2] + a1[2], a0[3] + a1[3]);
  o.z = pack2bf(a0[4] + a1[4], a0[5] + a1[5]);
  o.w = pack2bf(a0[6] + a1[6], a0[7] + a1[7]);
  *(uint4*)&T[(size_t)dst * 384 + k * 128 + l16 * 8] = o;
}

// C[M x 128] = A[M x 384](bf16) @ WT^T; MFMA 16x16x32 bf16; BM=128,BN=128,BK=32.
// Fused BN-stats epilogue: per-block column sum/sumsq -> atomicAdd to sums/sumsq.
__global__ __launch_bounds__(256) void k_gemm_mfma(const unsigned short* __restrict__ A,
                                                   const unsigned short* __restrict__ WT,
                                                   float* __restrict__ C,
                                                   float* __restrict__ sums,
                                                   float* __restrict__ sumsq, int M) {
  __shared__ unsigned short As[128][40];
  __shared__ unsigned short Bs[128][40];
  __shared__ float sSum[128], sSq[128];
  const int tid = threadIdx.x;
  const int m0 = blockIdx.x * 128;
  const int wave = tid >> 6, lane = tid & 63;
  const int wrow = wave >> 1, wcol = wave & 1;
  const int quad = lane >> 4, l16 = lane & 15;
  f32x4 acc[4][4] = {};

  for (int kb = 0; kb < 384; kb += 32) {
#pragma unroll
    for (int j = 0; j < 2; ++j) {
      int idx = tid + 256 * j;
      int rr = idx >> 2, kc = (idx & 3) * 8;
      int m = m0 + rr;
      float4 v = make_float4(0.f, 0.f, 0.f, 0.f);
      if (m < M) v = *(const float4*)&A[(size_t)m * 384 + kb + kc];
      *(float4*)&As[rr][kc] = v;
    }
#pragma unroll
    for (int j = 0; j < 2; ++j) {
      int idx = tid + 256 * j;
      int nn = idx >> 2, kc = (idx & 3) * 8;
      *(float4*)&Bs[nn][kc] = *(const float4*)&WT[(size_t)nn * 384 + kb + kc];
    }
    __syncthreads();
    short8 a[4], b[4];
#pragma unroll
    for (int t = 0; t < 4; ++t) a[t] = *(const short8*)&As[wrow * 64 + t * 16 + l16][quad * 8];
#pragma unroll
    for (int t = 0; t < 4; ++t) b[t] = *(const short8*)&Bs[wcol * 64 + t * 16 + l16][quad * 8];
#pragma unroll
    for (int rt = 0; rt < 4; ++rt)
#pragma unroll
      for (int ct = 0; ct < 4; ++ct)
        acc[rt][ct] = __builtin_amdgcn_mfma_f32_16x16x32_bf16(a[rt], b[ct], acc[rt][ct], 0, 0, 0);
    __syncthreads();
  }
  if (tid < 128) { sSum[tid] = 0.f; sSq[tid] = 0.f; }
  __syncthreads();
  float ps[4] = {}, pq[4] = {};
#pragma unroll
  for (int rt = 0; rt < 4; ++rt) {
#pragma unroll
    for (int reg = 0; reg < 4; ++reg) {
      int m = m0 + wrow * 64 + rt * 16 + quad * 4 + reg;
      if (m < M) {
#pragma unroll
        for (int ct = 0; ct < 4; ++ct) {
          float v = acc[rt][ct][reg];
          int col = wcol * 64 + ct * 16 + l16;
          C[(size_t)m * 128 + col] = v;
          ps[ct] += v; pq[ct] += v * v;
        }
      }
    }
  }
#pragma unroll
  for (int ct = 0; ct < 4; ++ct) {
    int col = wcol * 64 + ct * 16 + l16;
    atomicAdd(&sSum[col], ps[ct]);
    atomicAdd(&sSq[col], pq[ct]);
  }
  __syncthreads();
  if (tid < 128) {
    atomicAdd(&sums[tid], sSum[tid]);
    atomicAdd(&sumsq[tid], sSq[tid]);
  }
}

__global__ void k_finalize(const float* __restrict__ sums, const float* __restrict__ sumsq,
                           const float* __restrict__ gamma, const float* __restrict__ beta,
                           float* __restrict__ scale, float* __restrict__ bias, float invN) {
  int c = threadIdx.x;
  float mean = sums[c] * invN;
  float var = fmaxf(sumsq[c] * invN - mean * mean, 0.f);
  float sc = rsqrtf(var + 1e-5f) * gamma[c];
  scale[c] = sc;
  bias[c] = beta[c] - mean * sc;
}

// norm + tanh -> packed bf16 x-table
__global__ void k_norm(const float* __restrict__ agg, const float* __restrict__ scale,
                       const float* __restrict__ bias, unsigned int* __restrict__ xb, int nPairs) {
  int i = blockIdx.x * blockDim.x + threadIdx.x;
  if (i >= nPairs) return;
  int j = i & 63;
  float2 v = *(const float2*)&agg[(size_t)i * 2];
  float a = tanhf(fmaf(v.x, scale[2 * j], bias[2 * j]));
  float b = tanhf(fmaf(v.y, scale[2 * j + 1], bias[2 * j + 1]));
  xb[i] = pack2bf(a, b);
}

// one wave per triple: sum_d |x[h]+r[rel]-x[t]|
__global__ void k_score(const unsigned int* __restrict__ xb, const float* __restrict__ r,
                        const int* __restrict__ triples, float* __restrict__ out, int nT) {
  int gid = blockIdx.x * blockDim.x + threadIdx.x;
  int t = gid >> 6;
  if (t >= nT) return;
  int lane = gid & 63;
  int h = triples[t * 3], rel = triples[t * 3 + 1], tl = triples[t * 3 + 2];
  float2 a = bf2f(xb[(size_t)h * 64 + lane]);
  float2 b = *(const float2*)&r[(size_t)rel * 128 + lane * 2];
  float2 cc = bf2f(xb[(size_t)tl * 64 + lane]);
  float s = fabsf(a.x + b.x - cc.x) + fabsf(a.y + b.y - cc.y);
#pragma unroll
  for (int off = 32; off > 0; off >>= 1) s += __shfl_down(s, off);
  if (lane == 0) out[t] = s;
}

extern "C" void kernel_launch(void* const* d_in, const int* in_sizes, int n_in,
                              void* d_out, int out_size, void* d_ws, size_t ws_size,
                              hipStream_t stream) {
  const float* ent   = (const float*)d_in[0];
  const float* bases = (const float*)d_in[1];
  const float* coeff = (const float*)d_in[2];
  const float* selfr = (const float*)d_in[3];
  const float* W1    = (const float*)d_in[4];
  const float* relw1 = (const float*)d_in[5];
  const float* g1    = (const float*)d_in[6];
  const float* b1    = (const float*)d_in[7];
  const float* W2    = (const float*)d_in[8];
  const float* relw2 = (const float*)d_in[9];
  const float* g2    = (const float*)d_in[10];
  const float* b2    = (const float*)d_in[11];
  const int* ent_ids = (const int*)d_in[12];
  const int* ei      = (const int*)d_in[13];
  const int* et      = (const int*)d_in[14];
  const int* yk      = (const int*)d_in[15];
  const int* triples = (const int*)d_in[16];

  const int M  = in_sizes[0] / 128;   // 100000
  const int nE = in_sizes[14];        // 800000
  const int nT = in_sizes[16] / 3;    // 4096
  const int nKeys = M * 3;
  const int nScanBlocks = (nKeys + 1023) / 1024;

  // workspace layout (~162 MB)
  float* p = (float*)d_ws;
  float* rfull = p; p += 401 * 128;
  float* r1    = p; p += 401 * 128;
  float* r2    = p; p += 401 * 128;
  float* sums  = p; p += 128;
  float* sumsq = p; p += 128;
  float* scale = p; p += 128;
  float* bias  = p; p += 128;
  float* agg1  = p; p += (size_t)M * 128;            // GEMM output (fp32)
  unsigned int* entbf = (unsigned int*)agg1;         // alias: bf16 ent pre-GEMM
  unsigned int* xb    = (unsigned int*)p;            // M*64 packed bf16 x-table
  unsigned int* rfb   = xb + (size_t)M * 64;         // 401*64
  unsigned int* r1b   = rfb + 401 * 64;              // 401*64
  unsigned short* T   = (unsigned short*)(r1b + 401 * 64);  // M*384 bf16
  unsigned short* WT1 = T + (size_t)M * 384;
  unsigned short* WT2 = WT1 + 128 * 384;
  int* counts  = (int*)(WT2 + 128 * 384);
  int* offsets = counts + nKeys;
  int* cursor  = offsets + nKeys + 1;
  int* slocal  = cursor + nKeys;
  int* sblock  = slocal + nKeys;
  int* scarry  = sblock + nScanBlocks;
  unsigned int* packed = (unsigned int*)(scarry + nScanBlocks);

  float* out = (float*)d_out;

  const int mfmaBlocks = (M + 127) / 128;
  const int nPairs = M * 64;
  const int pairBlocks = (nPairs + 255) / 256;
  const int edgeBlocks = (nE + 255) / 256;
  const int aggBlocks  = (nKeys + 15) / 16;   // 4 keys/wave, 4 waves/block

  // relation chain (+ fused bf16 copies) + weight conversion
  k_rfull<<<401, 128, 0, stream>>>(coeff, bases, selfr, rfull, rfb);
  k_rmm<<<401, 128, 0, stream>>>(rfull, relw1, r1, r1b);
  k_rmm<<<401, 128, 0, stream>>>(r1, relw2, r2, nullptr);
  k_cvt<<<pairBlocks, 256, 0, stream>>>(ent, entbf, nPairs);
  k_wconv<<<192, 256, 0, stream>>>(W1, WT1);
  k_wconv<<<192, 256, 0, stream>>>(W2, WT2);

  // CSR over (dst, class) with packed (src|type<<20) payload
  hipMemsetAsync(counts, 0, (size_t)nKeys * sizeof(int), stream);
  k_hist<<<edgeBlocks, 256, 0, stream>>>(ei, yk, counts, nE);
  k_scan1<<<nScanBlocks, 1024, 0, stream>>>(counts, slocal, sblock, nKeys);
  k_scan2<<<1, 1024, 0, stream>>>(sblock, scarry, offsets, nKeys, nScanBlocks);
  k_scan3<<<nScanBlocks, 1024, 0, stream>>>(slocal, scarry, offsets, cursor, nKeys);
  k_fill<<<edgeBlocks, 256, 0, stream>>>(ei, et, yk, cursor, packed, nE);

  // ---- layer 1 ----
  hipMemsetAsync(sums, 0, 256 * sizeof(float), stream);   // sums+sumsq contiguous
  k_agg4<<<aggBlocks, 256, 0, stream>>>(entbf, ent_ids, rfb, offsets, packed, T, nKeys);
  k_gemm_mfma<<<mfmaBlocks, 256, 0, stream>>>(T, WT1, agg1, sums, sumsq, M);
  k_finalize<<<1, 128, 0, stream>>>(sums, sumsq, g1, b1, scale, bias, 1.0f / M);
  k_norm<<<pairBlocks, 256, 0, stream>>>(agg1, scale, bias, xb, nPairs);   // -> x1 (bf16)

  // ---- layer 2 ----
  hipMemsetAsync(sums, 0, 256 * sizeof(float), stream);
  k_agg4<<<aggBlocks, 256, 0, stream>>>(xb, nullptr, r1b, offsets, packed, T, nKeys);
  k_gemm_mfma<<<mfmaBlocks, 256, 0, stream>>>(T, WT2, agg1, sums, sumsq, M);
  k_finalize<<<1, 128, 0, stream>>>(sums, sumsq, g2, b2, scale, bias, 1.0f / M);
  k_norm<<<pairBlocks, 256, 0, stream>>>(agg1, scale, bias, xb, nPairs);   // -> x2 (bf16)

  // ---- scoring ----
  k_score<<<(nT * 64 + 255) / 256, 256, 0, stream>>>(xb, r2, triples, out, nT);
}